// Round 17
// baseline (90.164 us; speedup 1.0000x reference)
//
#include <hip/hip_runtime.h>
#include <hip/hip_bf16.h>
#include <math.h>

typedef __attribute__((ext_vector_type(8))) short short8;
typedef __attribute__((ext_vector_type(16))) float f32x16;

#define DHEAD 64
#define KVB 32
#define QB 32
#define NW 8     // waves per block (KV-split factor)
#define NWF 4    // fallback waves/block

// RNE fp32->bf16 pair pack (same rounding as v_cvt_pk_bf16_f32)
__device__ __forceinline__ unsigned pack2_bf16(float a, float b) {
  unsigned ua = __builtin_bit_cast(unsigned, a);
  unsigned ub = __builtin_bit_cast(unsigned, b);
  ua = (ua + 0x7fffu + ((ua >> 16) & 1u)) >> 16;
  ub = (ub + 0x7fffu + ((ub >> 16) & 1u)) >> 16;
  return (ua & 0xffffu) | (ub << 16);
}

union Frag { unsigned u[4]; short8 s; };

// ---- prep: Q,K,V -> bf16 PER-TILE FRAGMENT ORDER, NON-TEMPORAL stores (r15-proven) ----
__global__ __launch_bounds__(256)
void prep_f(const float* __restrict__ Q, const float* __restrict__ K,
            const float* __restrict__ V, unsigned short* __restrict__ Qf,
            unsigned short* __restrict__ Kf, unsigned short* __restrict__ Vf,
            const int* __restrict__ VL, int Lq, int Lk) {
  __shared__ float Vs[32][65];
  const int b = blockIdx.y, t = blockIdx.x, tid = threadIdx.x;
  const int LkT = Lk / 32, LqT = Lq / 32;
  const int kk = tid >> 6, lane = tid & 63;
  const int row = lane & 31, colb = kk * 16 + ((lane >> 5) & 1) * 8;
  const float cQ = 0.125f * 1.4426950408889634f;  // (1/sqrt(64))*log2(e)

  if (t < LqT) {
    const float* src = Q + (((size_t)b * Lq + t * 32 + row) * DHEAD + colb);
    Frag fr;
    #pragma unroll
    for (int j = 0; j < 4; ++j)
      fr.u[j] = pack2_bf16(src[2 * j] * cQ, src[2 * j + 1] * cQ);
    __builtin_nontemporal_store(fr.s, (short8*)(Qf + ((size_t)(b * LqT + t)) * 2048 + tid * 8));
  }

  const int vl = VL[b];
  int nkb = (vl == 0) ? LkT : ((vl + 31) / 32);
  if (nkb > LkT) nkb = LkT;

  if (t < nkb) {
    const size_t base = ((size_t)b * Lk + t * 32) * DHEAD;
    {  // K convert
      const float* src = K + base + (size_t)row * DHEAD + colb;
      Frag fr;
      #pragma unroll
      for (int j = 0; j < 4; ++j)
        fr.u[j] = pack2_bf16(src[2 * j], src[2 * j + 1]);
      __builtin_nontemporal_store(fr.s, (short8*)(Kf + ((size_t)(b * LkT + t)) * 2048 + tid * 8));
    }
    for (int e = tid; e < 32 * DHEAD; e += 256) Vs[e >> 6][e & 63] = V[base + e];
    __syncthreads();
    const int region = tid >> 6;              // 0..3 = half*2 + vkk
    const int vkk = region & 1, half = region >> 1;
    const int krow = vkk * 16 + ((lane >> 5) & 1) * 8;
    const int d = half * 32 + (lane & 31);
    Frag fv;
    #pragma unroll
    for (int j = 0; j < 4; ++j)
      fv.u[j] = pack2_bf16(Vs[krow + 2 * j][d], Vs[krow + 2 * j + 1][d]);
    __builtin_nontemporal_store(fv.s, (short8*)(Vf + ((size_t)(b * LkT + t)) * 2048 + tid * 8));
  }
}

// ---- one KV-tile step with DEEP prefetch: uses kc/vc, prefetches K[t+2NW]->kpf, V[t+NW]->vpf ----
__device__ __forceinline__ void tile_body(
    int t, int nkb, int vl, int lane, int hi,
    const unsigned short* __restrict__ kb, const unsigned short* __restrict__ vb,
    const short8 (&qf)[4], short8 (&kc)[4], short8 (&kpf)[4],
    short8 (&vc)[4], short8 (&vpf)[4],
    f32x16& o0, f32x16& o1, float& m, float& l) {
  const float MASKV = -1442695.04f;  // -1e6 * log2(e)

  // S^T = K * Q^T (log2 domain)
  f32x16 s = {};
  #pragma unroll
  for (int kk = 0; kk < 4; ++kk)
    s = __builtin_amdgcn_mfma_f32_32x32x16_bf16(kc[kk], qf[kk], s, 0, 0, 0);

  // deep prefetch: K two tiles ahead, V one tile ahead (~2 tiles of latency cover)
  if (t + 2 * NW < nkb) {
    const unsigned short* ktn = kb + (size_t)(t + 2 * NW) * 2048;
    #pragma unroll
    for (int kk = 0; kk < 4; ++kk)
      kpf[kk] = *(const short8*)(ktn + kk * 512 + lane * 8);
  }
  if (t + NW < nkb) {
    const unsigned short* vtn = vb + (size_t)(t + NW) * 2048;
    #pragma unroll
    for (int kk = 0; kk < 4; ++kk)
      vpf[kk] = *(const short8*)(vtn + kk * 512 + lane * 8);
  }

  const int key0 = t * KVB;
  if (key0 + KVB > vl) {
    #pragma unroll
    for (int r = 0; r < 16; ++r) {
      const int key = key0 + (r & 3) + 8 * (r >> 2) + 4 * hi;
      if (key >= vl) s[r] = MASKV;
    }
  }

  float t0 = fmaxf(s[0], s[1]),  t1 = fmaxf(s[2], s[3]);
  float t2 = fmaxf(s[4], s[5]),  t3 = fmaxf(s[6], s[7]);
  float t4 = fmaxf(s[8], s[9]),  t5 = fmaxf(s[10], s[11]);
  float t6 = fmaxf(s[12], s[13]), t7 = fmaxf(s[14], s[15]);
  t0 = fmaxf(t0, t1); t2 = fmaxf(t2, t3); t4 = fmaxf(t4, t5); t6 = fmaxf(t6, t7);
  t0 = fmaxf(t0, t2); t4 = fmaxf(t4, t6);
  float tm = fmaxf(t0, t4);
  tm = fmaxf(tm, __shfl_xor(tm, 32));

  if (__any(tm > m)) {          // exact defer-max
    const float mnew  = fmaxf(m, tm);
    const float alpha = exp2f(m - mnew);  // first iter: exp2(-inf) = 0
    #pragma unroll
    for (int r = 0; r < 16; ++r) { o0[r] *= alpha; o1[r] *= alpha; }
    l *= alpha;
    m = mnew;
  }
  #pragma unroll
  for (int r = 0; r < 16; ++r) s[r] = exp2f(s[r] - m);
  float u0 = s[0] + s[1],  u1 = s[2] + s[3];
  float u2 = s[4] + s[5],  u3 = s[6] + s[7];
  float u4 = s[8] + s[9],  u5 = s[10] + s[11];
  float u6 = s[12] + s[13], u7 = s[14] + s[15];
  u0 += u1; u2 += u3; u4 += u5; u6 += u7; u0 += u2; u4 += u6;
  l += u0 + u4 + __shfl_xor(u0 + u4, 32);

  short8 pf[2];
  #pragma unroll
  for (int kk = 0; kk < 2; ++kk) {
    const unsigned A0 = pack2_bf16(s[8 * kk + 0], s[8 * kk + 1]);
    const unsigned B0 = pack2_bf16(s[8 * kk + 2], s[8 * kk + 3]);
    const unsigned C0 = pack2_bf16(s[8 * kk + 4], s[8 * kk + 5]);
    const unsigned D0 = pack2_bf16(s[8 * kk + 6], s[8 * kk + 7]);
    const unsigned sA = (unsigned)__shfl_xor((int)A0, 32);
    const unsigned sB = (unsigned)__shfl_xor((int)B0, 32);
    const unsigned sC = (unsigned)__shfl_xor((int)C0, 32);
    const unsigned sD = (unsigned)__shfl_xor((int)D0, 32);
    Frag fr;
    fr.u[0] = hi ? sC : A0;
    fr.u[1] = hi ? sD : B0;
    fr.u[2] = hi ? C0 : sA;
    fr.u[3] = hi ? D0 : sB;
    pf[kk] = fr.s;
  }

  o0 = __builtin_amdgcn_mfma_f32_32x32x16_bf16(vc[0], pf[0], o0, 0, 0, 0);
  o1 = __builtin_amdgcn_mfma_f32_32x32x16_bf16(vc[2], pf[0], o1, 0, 0, 0);
  o0 = __builtin_amdgcn_mfma_f32_32x32x16_bf16(vc[1], pf[1], o0, 0, 0, 0);
  o1 = __builtin_amdgcn_mfma_f32_32x32x16_bf16(vc[3], pf[1], o1, 0, 0, 0);
}

// ---- fused pass: 2-D grid (qt, b); 8 waves split KV; triple-K/double-V pipeline ----
__global__ __launch_bounds__(NW * 64, 2)
void fa8(const unsigned short* __restrict__ Qf, const unsigned short* __restrict__ Kf,
         const unsigned short* __restrict__ Vf, const int* __restrict__ VL,
         float* __restrict__ Og, int Lq, int Lk, int nqt) {
  __shared__ float OLs[4][QB][DHEAD + 1];   // staged tree-merge slots
  __shared__ float mL[4][QB];
  __shared__ float lL[4][QB];
  __shared__ float FIN[QB][DHEAD + 2];      // output coalescing buffer

  const int tid  = threadIdx.x;
  const int w    = tid >> 6;
  const int lane = tid & 63;
  const int l31  = lane & 31;
  const int hi   = lane >> 5;
  const int qt   = blockIdx.x;
  const int b    = blockIdx.y;
  const int vl   = VL[b];

  const int LkT = Lk / KVB;
  int nkb = (vl == 0) ? LkT : ((vl + KVB - 1) / KVB);
  if (nkb > LkT) nkb = LkT;

  const unsigned short* qtile = Qf + ((size_t)(b * nqt + qt)) * 2048;
  short8 qf[4];
  #pragma unroll
  for (int kk = 0; kk < 4; ++kk)
    qf[kk] = *(const short8*)(qtile + kk * 512 + lane * 8);

  const unsigned short* kb = Kf + (size_t)b * LkT * 2048;
  const unsigned short* vb = Vf + (size_t)b * LkT * 2048;

  f32x16 o0 = {};  // O^T rows d=0..31  (col = query = lane&31)
  f32x16 o1 = {};  // O^T rows d=32..63
  float m = -INFINITY;
  float l = 0.0f;

  // 3-buffer K / 2-buffer V software pipeline (period-6 static rotation, rule #20)
  int t = w;
  if (t < nkb) {
    short8 kA[4], kB[4], kC[4], vA[4], vB[4];
    {
      const unsigned short* kt = kb + (size_t)t * 2048;
      const unsigned short* vt = vb + (size_t)t * 2048;
      #pragma unroll
      for (int kk = 0; kk < 4; ++kk) {
        kA[kk] = *(const short8*)(kt + kk * 512 + lane * 8);
        vA[kk] = *(const short8*)(vt + kk * 512 + lane * 8);
      }
      if (t + NW < nkb) {
        const unsigned short* kt2 = kb + (size_t)(t + NW) * 2048;
        #pragma unroll
        for (int kk = 0; kk < 4; ++kk)
          kB[kk] = *(const short8*)(kt2 + kk * 512 + lane * 8);
      }
    }
    while (true) {
      tile_body(t, nkb, vl, lane, hi, kb, vb, qf, kA, kC, vA, vB, o0, o1, m, l);
      t += NW; if (t >= nkb) break;
      tile_body(t, nkb, vl, lane, hi, kb, vb, qf, kB, kA, vB, vA, o0, o1, m, l);
      t += NW; if (t >= nkb) break;
      tile_body(t, nkb, vl, lane, hi, kb, vb, qf, kC, kB, vA, vB, o0, o1, m, l);
      t += NW; if (t >= nkb) break;
      tile_body(t, nkb, vl, lane, hi, kb, vb, qf, kA, kC, vB, vA, o0, o1, m, l);
      t += NW; if (t >= nkb) break;
      tile_body(t, nkb, vl, lane, hi, kb, vb, qf, kB, kA, vA, vB, o0, o1, m, l);
      t += NW; if (t >= nkb) break;
      tile_body(t, nkb, vl, lane, hi, kb, vb, qf, kC, kB, vB, vA, o0, o1, m, l);
      t += NW; if (t >= nkb) break;
    }
  }

  // ---- staged pairwise tree merge, 4 slots, NaN-safe (l>0 guards) ----
  #pragma unroll
  for (int ph = 0; ph < 3; ++ph) {
    const int wlo  = (ph == 0) ? 4 : (ph == 1) ? 2 : 1;
    const int wcnt = wlo == 1 ? 1 : wlo;

    if (w >= wlo && w < wlo + wcnt) {
      const int s = w - wlo;
      if (hi == 0) { mL[s][l31] = m; lL[s][l31] = l; }
      #pragma unroll
      for (int r = 0; r < 16; ++r) {
        const int dr = (r & 3) + 8 * (r >> 2) + 4 * hi;
        OLs[s][l31][dr]      = o0[r];
        OLs[s][l31][dr + 32] = o1[r];
      }
    }
    __syncthreads();
    if (w < wcnt) {
      const int s = w;
      const float m2 = mL[s][l31];
      const float l2 = lL[s][l31];
      const float M  = fmaxf(m, m2);
      const float a  = (l  > 0.f) ? exp2f(m - M)  : 0.f;   // guard exp2(-inf-(-inf))
      const float a2 = (l2 > 0.f) ? exp2f(m2 - M) : 0.f;
      #pragma unroll
      for (int r = 0; r < 16; ++r) {
        const int dr = (r & 3) + 8 * (r >> 2) + 4 * hi;
        o0[r] = o0[r] * a + OLs[s][l31][dr]      * a2;
        o1[r] = o1[r] * a + OLs[s][l31][dr + 32] * a2;
      }
      l = l * a + l2 * a2;
      m = M;
    }
    __syncthreads();
  }

  // wave 0 holds final (m,l,O^T): normalize into FIN, coalesced store
  if (w == 0) {
    const float rl = (l > 0.f) ? 1.0f / l : 0.0f;
    #pragma unroll
    for (int r = 0; r < 16; ++r) {
      const int dr = (r & 3) + 8 * (r >> 2) + 4 * hi;
      FIN[l31][dr]      = o0[r] * rl;
      FIN[l31][dr + 32] = o1[r] * rl;
    }
  }
  __syncthreads();
  const size_t base = ((size_t)b * Lq + (size_t)qt * QB) * DHEAD;
  for (int e = tid; e < QB * DHEAD; e += NW * 64)
    Og[base + e] = FIN[e >> 6][e & 63];
}

// ---- fallback (round-2 kernel, on-the-fly conversion) ----
__global__ __launch_bounds__(NWF * 64)
void fa_fwd(const float* __restrict__ Qg, const float* __restrict__ Kg,
            const float* __restrict__ Vg, const int* __restrict__ VL,
            float* __restrict__ Og, int Lq, int Lk) {
  __shared__ float OLs[NWF][QB][DHEAD + 1];
  __shared__ float mLs[NWF][QB];
  __shared__ float lLs[NWF][QB];

  const int tid  = threadIdx.x;
  const int w    = tid >> 6;
  const int lane = tid & 63;
  const int l31  = lane & 31;
  const int hi   = lane >> 5;
  const int q0   = blockIdx.x * QB;
  const int b    = blockIdx.y;
  const int vl   = VL[b];

  const float* Qb = Qg + (size_t)b * Lq * DHEAD;
  const float* Kb = Kg + (size_t)b * Lk * DHEAD;
  const float* Vb = Vg + (size_t)b * Lk * DHEAD;

  const float cQ = 0.125f * 1.4426950408889634f;
  short8 qf[4];
  {
    const float* qrow = Qb + (size_t)(q0 + l31) * DHEAD + hi * 8;
    #pragma unroll
    for (int kk = 0; kk < 4; ++kk) {
      Frag fr;
      #pragma unroll
      for (int j = 0; j < 4; ++j)
        fr.u[j] = pack2_bf16(qrow[kk * 16 + 2 * j] * cQ,
                             qrow[kk * 16 + 2 * j + 1] * cQ);
      qf[kk] = fr.s;
    }
  }

  f32x16 o0 = {};
  f32x16 o1 = {};
  float m = -INFINITY;
  float l = 0.0f;

  int nkb = (vl == 0) ? (Lk / KVB) : ((vl + KVB - 1) / KVB);
  if (nkb > Lk / KVB) nkb = Lk / KVB;
  const int nt = (nkb > w) ? ((nkb - w + NWF - 1) / NWF) : 0;

  const float MASKV = -1442695.04f;

  float kraw[32], vraw[32];

  if (nt > 0) {
    const float* krow = Kb + (size_t)(w * KVB + l31) * DHEAD + hi * 8;
    #pragma unroll
    for (int kk = 0; kk < 4; ++kk)
      #pragma unroll
      for (int j = 0; j < 8; ++j) kraw[kk * 8 + j] = krow[kk * 16 + j];
  }

  for (int t = 0; t < nt; ++t) {
    const int key0 = (w + t * NWF) * KVB;

    short8 kf[4];
    #pragma unroll
    for (int kk = 0; kk < 4; ++kk) {
      Frag fr;
      #pragma unroll
      for (int j = 0; j < 4; ++j)
        fr.u[j] = pack2_bf16(kraw[kk * 8 + 2 * j], kraw[kk * 8 + 2 * j + 1]);
      kf[kk] = fr.s;
    }

    #pragma unroll
    for (int kk = 0; kk < 2; ++kk) {
      const float* vrow = Vb + (size_t)(key0 + kk * 16 + hi * 8) * DHEAD + l31;
      #pragma unroll
      for (int j = 0; j < 8; ++j) {
        vraw[kk * 16 + j]     = vrow[j * DHEAD];
        vraw[kk * 16 + 8 + j] = vrow[j * DHEAD + 32];
      }
    }

    f32x16 s = {};
    #pragma unroll
    for (int kk = 0; kk < 4; ++kk)
      s = __builtin_amdgcn_mfma_f32_32x32x16_bf16(kf[kk], qf[kk], s, 0, 0, 0);

    if (t + 1 < nt) {
      const float* krow = Kb + (size_t)(key0 + NWF * KVB + l31) * DHEAD + hi * 8;
      #pragma unroll
      for (int kk = 0; kk < 4; ++kk)
        #pragma unroll
        for (int j = 0; j < 8; ++j) kraw[kk * 8 + j] = krow[kk * 16 + j];
    }

    if (key0 + KVB > vl) {
      #pragma unroll
      for (int r = 0; r < 16; ++r) {
        const int key = key0 + (r & 3) + 8 * (r >> 2) + 4 * hi;
        if (key >= vl) s[r] = MASKV;
      }
    }

    float t0 = fmaxf(s[0], s[1]),  t1 = fmaxf(s[2], s[3]);
    float t2 = fmaxf(s[4], s[5]),  t3 = fmaxf(s[6], s[7]);
    float t4 = fmaxf(s[8], s[9]),  t5 = fmaxf(s[10], s[11]);
    float t6 = fmaxf(s[12], s[13]), t7 = fmaxf(s[14], s[15]);
    t0 = fmaxf(t0, t1); t2 = fmaxf(t2, t3); t4 = fmaxf(t4, t5); t6 = fmaxf(t6, t7);
    t0 = fmaxf(t0, t2); t4 = fmaxf(t4, t6);
    float tm = fmaxf(t0, t4);
    tm = fmaxf(tm, __shfl_xor(tm, 32));
    const float mnew  = fmaxf(m, tm);
    const float alpha = exp2f(m - mnew);
    #pragma unroll
    for (int r = 0; r < 16; ++r) s[r] = exp2f(s[r] - mnew);
    float u0 = s[0] + s[1],  u1 = s[2] + s[3];
    float u2 = s[4] + s[5],  u3 = s[6] + s[7];
    float u4 = s[8] + s[9],  u5 = s[10] + s[11];
    float u6 = s[12] + s[13], u7 = s[14] + s[15];
    u0 += u1; u2 += u3; u4 += u5; u6 += u7; u0 += u2; u4 += u6;
    float sum = u0 + u4;
    sum += __shfl_xor(sum, 32);
    l = l * alpha + sum;
    m = mnew;
    #pragma unroll
    for (int r = 0; r < 16; ++r) { o0[r] *= alpha; o1[r] *= alpha; }

    short8 pf[2];
    #pragma unroll
    for (int kk = 0; kk < 2; ++kk) {
      const unsigned A0 = pack2_bf16(s[8 * kk + 0], s[8 * kk + 1]);
      const unsigned B0 = pack2_bf16(s[8 * kk + 2], s[8 * kk + 3]);
      const unsigned C0 = pack2_bf16(s[8 * kk + 4], s[8 * kk + 5]);
      const unsigned D0 = pack2_bf16(s[8 * kk + 6], s[8 * kk + 7]);
      const unsigned sA = (unsigned)__shfl_xor((int)A0, 32);
      const unsigned sB = (unsigned)__shfl_xor((int)B0, 32);
      const unsigned sC = (unsigned)__shfl_xor((int)C0, 32);
      const unsigned sD = (unsigned)__shfl_xor((int)D0, 32);
      Frag fr;
      fr.u[0] = hi ? sC : A0;
      fr.u[1] = hi ? sD : B0;
      fr.u[2] = hi ? C0 : sA;
      fr.u[3] = hi ? D0 : sB;
      pf[kk] = fr.s;
    }

    #pragma unroll
    for (int kk = 0; kk < 2; ++kk) {
      Frag f0, f1;
      #pragma unroll
      for (int j = 0; j < 4; ++j) {
        f0.u[j] = pack2_bf16(vraw[kk * 16 + 2 * j],     vraw[kk * 16 + 2 * j + 1]);
        f1.u[j] = pack2_bf16(vraw[kk * 16 + 8 + 2 * j], vraw[kk * 16 + 8 + 2 * j + 1]);
      }
      o0 = __builtin_amdgcn_mfma_f32_32x32x16_bf16(f0.s, pf[kk], o0, 0, 0, 0);
      o1 = __builtin_amdgcn_mfma_f32_32x32x16_bf16(f1.s, pf[kk], o1, 0, 0, 0);
    }
  }

  if (hi == 0) { mLs[w][l31] = m; lLs[w][l31] = l; }
  #pragma unroll
  for (int r = 0; r < 16; ++r) {
    const int dr = (r & 3) + 8 * (r >> 2) + 4 * hi;
    OLs[w][l31][dr]      = o0[r];
    OLs[w][l31][dr + 32] = o1[r];
  }
  __syncthreads();

  for (int e = tid; e < QB * DHEAD; e += NWF * 64) {
    const int q = e >> 6;
    const int d = e & 63;
    float M = mLs[0][q];
    #pragma unroll
    for (int ww = 1; ww < NWF; ++ww) M = fmaxf(M, mLs[ww][q]);
    float L = 0.f, acc = 0.f;
    #pragma unroll
    for (int ww = 0; ww < NWF; ++ww) {
      const float wgt = exp2f(mLs[ww][q] - M);
      L   += lLs[ww][q] * wgt;
      acc += OLs[ww][q][d] * wgt;
    }
    Og[((size_t)b * Lq + q0 + q) * DHEAD + d] = acc / L;
  }
}

extern "C" void kernel_launch(void* const* d_in, const int* in_sizes, int n_in,
                              void* d_out, int out_size, void* d_ws, size_t ws_size,
                              hipStream_t stream) {
  const float* Q  = (const float*)d_in[0];
  const float* K  = (const float*)d_in[1];
  const float* V  = (const float*)d_in[2];
  const int*   VL = (const int*)d_in[3];
  float* O = (float*)d_out;

  const int B  = in_sizes[3];                  // 8
  const int Lq = in_sizes[0] / (B * DHEAD);    // 2048
  const int Lk = in_sizes[1] / (B * DHEAD);    // 2048
  const int nqt = Lq / QB;                     // 64

  const size_t qfE = (size_t)B * Lq * DHEAD;   // elements
  const size_t kfE = (size_t)B * Lk * DHEAD;
  const size_t need = (qfE + kfE * 2) * 2;     // Qf + Kf + Vf (bf16)

  if (ws_size >= need) {
    unsigned short* Qf = (unsigned short*)d_ws;
    unsigned short* Kf = Qf + qfE;
    unsigned short* Vf = Kf + kfE;

    const int maxT = (Lq > Lk ? Lq : Lk) / 32;
    dim3 pgrid(maxT, B);
    prep_f<<<pgrid, 256, 0, stream>>>(Q, K, V, Qf, Kf, Vf, VL, Lq, Lk);
    dim3 g1(nqt, B);
    fa8<<<g1, NW * 64, 0, stream>>>(Qf, Kf, Vf, VL, O, Lq, Lk, nqt);
  } else {
    dim3 grid(Lq / QB, B);
    fa_fwd<<<grid, NWF * 64, 0, stream>>>(Q, K, V, VL, O, Lq, Lk);
  }
}

// Round 18
// 39.380 us; speedup vs baseline: 2.2896x; 2.2896x over previous
//
#include <hip/hip_runtime.h>
#include <hip/hip_bf16.h>
#include <math.h>

typedef __attribute__((ext_vector_type(8))) short short8;
typedef __attribute__((ext_vector_type(16))) float f32x16;

#define DHEAD 64
#define KVB 32
#define QB 32
#define NW 8     // waves per block (KV-split factor)
#define NWF 4    // fallback waves/block

// RNE fp32->bf16 pair pack (same rounding as v_cvt_pk_bf16_f32)
__device__ __forceinline__ unsigned pack2_bf16(float a, float b) {
  unsigned ua = __builtin_bit_cast(unsigned, a);
  unsigned ub = __builtin_bit_cast(unsigned, b);
  ua = (ua + 0x7fffu + ((ua >> 16) & 1u)) >> 16;
  ub = (ub + 0x7fffu + ((ub >> 16) & 1u)) >> 16;
  return (ua & 0xffffu) | (ub << 16);
}

union Frag { unsigned u[4]; short8 s; };

// ---- prep: Q,K,V -> bf16 PER-TILE FRAGMENT ORDER, NON-TEMPORAL stores (r15-proven) ----
__global__ __launch_bounds__(256)
void prep_f(const float* __restrict__ Q, const float* __restrict__ K,
            const float* __restrict__ V, unsigned short* __restrict__ Qf,
            unsigned short* __restrict__ Kf, unsigned short* __restrict__ Vf,
            const int* __restrict__ VL, int Lq, int Lk) {
  __shared__ float Vs[32][65];
  const int b = blockIdx.y, t = blockIdx.x, tid = threadIdx.x;
  const int LkT = Lk / 32, LqT = Lq / 32;
  const int kk = tid >> 6, lane = tid & 63;
  const int row = lane & 31, colb = kk * 16 + ((lane >> 5) & 1) * 8;
  const float cQ = 0.125f * 1.4426950408889634f;  // (1/sqrt(64))*log2(e)

  if (t < LqT) {
    const float* src = Q + (((size_t)b * Lq + t * 32 + row) * DHEAD + colb);
    Frag fr;
    #pragma unroll
    for (int j = 0; j < 4; ++j)
      fr.u[j] = pack2_bf16(src[2 * j] * cQ, src[2 * j + 1] * cQ);
    __builtin_nontemporal_store(fr.s, (short8*)(Qf + ((size_t)(b * LqT + t)) * 2048 + tid * 8));
  }

  const int vl = VL[b];
  int nkb = (vl == 0) ? LkT : ((vl + 31) / 32);
  if (nkb > LkT) nkb = LkT;

  if (t < nkb) {
    const size_t base = ((size_t)b * Lk + t * 32) * DHEAD;
    {  // K convert
      const float* src = K + base + (size_t)row * DHEAD + colb;
      Frag fr;
      #pragma unroll
      for (int j = 0; j < 4; ++j)
        fr.u[j] = pack2_bf16(src[2 * j], src[2 * j + 1]);
      __builtin_nontemporal_store(fr.s, (short8*)(Kf + ((size_t)(b * LkT + t)) * 2048 + tid * 8));
    }
    for (int e = tid; e < 32 * DHEAD; e += 256) Vs[e >> 6][e & 63] = V[base + e];
    __syncthreads();
    const int region = tid >> 6;              // 0..3 = half*2 + vkk
    const int vkk = region & 1, half = region >> 1;
    const int krow = vkk * 16 + ((lane >> 5) & 1) * 8;
    const int d = half * 32 + (lane & 31);
    Frag fv;
    #pragma unroll
    for (int j = 0; j < 4; ++j)
      fv.u[j] = pack2_bf16(Vs[krow + 2 * j][d], Vs[krow + 2 * j + 1][d]);
    __builtin_nontemporal_store(fv.s, (short8*)(Vf + ((size_t)(b * LkT + t)) * 2048 + tid * 8));
  }
}

// ---- one KV-tile step (r15-proven): V loads -> S MFMA -> K prefetch -> softmax -> PV ----
__device__ __forceinline__ void tile_body(
    int t, int nkb, int vl, int lane, int hi,
    const unsigned short* __restrict__ kb, const unsigned short* __restrict__ vb,
    const short8 (&qf)[4], short8 (&kc)[4], short8 (&kn)[4],
    f32x16& o0, f32x16& o1, float& m, float& l) {
  const float MASKV = -1442695.04f;  // -1e6 * log2(e)

  const unsigned short* vt = vb + (size_t)t * 2048;
  short8 vf0[2], vf1[2];
  #pragma unroll
  for (int kk = 0; kk < 2; ++kk) {
    vf0[kk] = *(const short8*)(vt + kk * 512 + lane * 8);
    vf1[kk] = *(const short8*)(vt + (2 + kk) * 512 + lane * 8);
  }

  f32x16 s = {};
  #pragma unroll
  for (int kk = 0; kk < 4; ++kk)
    s = __builtin_amdgcn_mfma_f32_32x32x16_bf16(kc[kk], qf[kk], s, 0, 0, 0);

  const int tn = t + NW;
  if (tn < nkb) {
    const unsigned short* ktn = kb + (size_t)tn * 2048;
    #pragma unroll
    for (int kk = 0; kk < 4; ++kk)
      kn[kk] = *(const short8*)(ktn + kk * 512 + lane * 8);
  }

  const int key0 = t * KVB;
  if (key0 + KVB > vl) {
    #pragma unroll
    for (int r = 0; r < 16; ++r) {
      const int key = key0 + (r & 3) + 8 * (r >> 2) + 4 * hi;
      if (key >= vl) s[r] = MASKV;
    }
  }

  float t0 = fmaxf(s[0], s[1]),  t1 = fmaxf(s[2], s[3]);
  float t2 = fmaxf(s[4], s[5]),  t3 = fmaxf(s[6], s[7]);
  float t4 = fmaxf(s[8], s[9]),  t5 = fmaxf(s[10], s[11]);
  float t6 = fmaxf(s[12], s[13]), t7 = fmaxf(s[14], s[15]);
  t0 = fmaxf(t0, t1); t2 = fmaxf(t2, t3); t4 = fmaxf(t4, t5); t6 = fmaxf(t6, t7);
  t0 = fmaxf(t0, t2); t4 = fmaxf(t4, t6);
  float tm = fmaxf(t0, t4);
  tm = fmaxf(tm, __shfl_xor(tm, 32));

  if (__any(tm > m)) {          // exact defer-max
    const float mnew  = fmaxf(m, tm);
    const float alpha = exp2f(m - mnew);  // first iter: exp2(-inf) = 0
    #pragma unroll
    for (int r = 0; r < 16; ++r) { o0[r] *= alpha; o1[r] *= alpha; }
    l *= alpha;
    m = mnew;
  }
  #pragma unroll
  for (int r = 0; r < 16; ++r) s[r] = exp2f(s[r] - m);
  float u0 = s[0] + s[1],  u1 = s[2] + s[3];
  float u2 = s[4] + s[5],  u3 = s[6] + s[7];
  float u4 = s[8] + s[9],  u5 = s[10] + s[11];
  float u6 = s[12] + s[13], u7 = s[14] + s[15];
  u0 += u1; u2 += u3; u4 += u5; u6 += u7; u0 += u2; u4 += u6;
  l += u0 + u4 + __shfl_xor(u0 + u4, 32);

  short8 pf[2];
  #pragma unroll
  for (int kk = 0; kk < 2; ++kk) {
    const unsigned A0 = pack2_bf16(s[8 * kk + 0], s[8 * kk + 1]);
    const unsigned B0 = pack2_bf16(s[8 * kk + 2], s[8 * kk + 3]);
    const unsigned C0 = pack2_bf16(s[8 * kk + 4], s[8 * kk + 5]);
    const unsigned D0 = pack2_bf16(s[8 * kk + 6], s[8 * kk + 7]);
    const unsigned sA = (unsigned)__shfl_xor((int)A0, 32);
    const unsigned sB = (unsigned)__shfl_xor((int)B0, 32);
    const unsigned sC = (unsigned)__shfl_xor((int)C0, 32);
    const unsigned sD = (unsigned)__shfl_xor((int)D0, 32);
    Frag fr;
    fr.u[0] = hi ? sC : A0;
    fr.u[1] = hi ? sD : B0;
    fr.u[2] = hi ? C0 : sA;
    fr.u[3] = hi ? D0 : sB;
    pf[kk] = fr.s;
  }

  #pragma unroll
  for (int kk = 0; kk < 2; ++kk) {
    o0 = __builtin_amdgcn_mfma_f32_32x32x16_bf16(vf0[kk], pf[kk], o0, 0, 0, 0);
    o1 = __builtin_amdgcn_mfma_f32_32x32x16_bf16(vf1[kk], pf[kk], o1, 0, 0, 0);
  }
}

// ---- fused pass: 1-D grid with LPT batch ordering; 8 waves split KV; no spill ----
__global__ __launch_bounds__(NW * 64, 2)
void fa8(const unsigned short* __restrict__ Qf, const unsigned short* __restrict__ Kf,
         const unsigned short* __restrict__ Vf, const int* __restrict__ VL,
         float* __restrict__ Og, int Lq, int Lk, int nqt, int B) {
  __shared__ float OLs[4][QB][DHEAD + 1];   // staged tree-merge slots
  __shared__ float mL[4][QB];
  __shared__ float lL[4][QB];
  __shared__ float FIN[QB][DHEAD + 2];      // output coalescing buffer

  const int tid  = threadIdx.x;
  const int w    = tid >> 6;
  const int lane = tid & 63;
  const int l31  = lane & 31;
  const int hi   = lane >> 5;
  const int LkT  = Lk / KVB;

  // LPT schedule: bslot-th block group takes the batch with bslot-th LARGEST work.
  // All threads compute the same mapping from VL (deterministic; ~B^2 scalar ops).
  const int bslot = blockIdx.x / nqt;
  const int qt    = blockIdx.x % nqt;
  int b = 0;
  for (int j = 0; j < B; ++j) {
    const int vlj = VL[j];
    int nkj = (vlj == 0) ? LkT : ((vlj + KVB - 1) / KVB);
    if (nkj > LkT) nkj = LkT;
    int r = 0;
    for (int i2 = 0; i2 < B; ++i2) {
      const int vli = VL[i2];
      int nki = (vli == 0) ? LkT : ((vli + KVB - 1) / KVB);
      if (nki > LkT) nki = LkT;
      if (nki > nkj || (nki == nkj && i2 < j)) ++r;
    }
    if (r == bslot) b = j;
  }
  const int vl = VL[b];

  int nkb = (vl == 0) ? LkT : ((vl + KVB - 1) / KVB);
  if (nkb > LkT) nkb = LkT;

  const unsigned short* qtile = Qf + ((size_t)(b * nqt + qt)) * 2048;
  short8 qf[4];
  #pragma unroll
  for (int kk = 0; kk < 4; ++kk)
    qf[kk] = *(const short8*)(qtile + kk * 512 + lane * 8);

  const unsigned short* kb = Kf + (size_t)b * LkT * 2048;
  const unsigned short* vb = Vf + (size_t)b * LkT * 2048;

  f32x16 o0 = {};  // O^T rows d=0..31  (col = query = lane&31)
  f32x16 o1 = {};  // O^T rows d=32..63
  float m = -INFINITY;
  float l = 0.0f;

  // K double-buffer software pipeline (static indexing)
  int t = w;
  if (t < nkb) {
    short8 kA[4], kB[4];
    const unsigned short* kt = kb + (size_t)t * 2048;
    #pragma unroll
    for (int kk = 0; kk < 4; ++kk)
      kA[kk] = *(const short8*)(kt + kk * 512 + lane * 8);
    while (true) {
      tile_body(t, nkb, vl, lane, hi, kb, vb, qf, kA, kB, o0, o1, m, l);
      t += NW; if (t >= nkb) break;
      tile_body(t, nkb, vl, lane, hi, kb, vb, qf, kB, kA, o0, o1, m, l);
      t += NW; if (t >= nkb) break;
    }
  }

  // ---- staged pairwise tree merge, 4 slots, NaN-safe (l>0 guards) ----
  #pragma unroll
  for (int ph = 0; ph < 3; ++ph) {
    const int wlo  = (ph == 0) ? 4 : (ph == 1) ? 2 : 1;
    const int wcnt = wlo == 1 ? 1 : wlo;

    if (w >= wlo && w < wlo + wcnt) {
      const int s = w - wlo;
      if (hi == 0) { mL[s][l31] = m; lL[s][l31] = l; }
      #pragma unroll
      for (int r = 0; r < 16; ++r) {
        const int dr = (r & 3) + 8 * (r >> 2) + 4 * hi;
        OLs[s][l31][dr]      = o0[r];
        OLs[s][l31][dr + 32] = o1[r];
      }
    }
    __syncthreads();
    if (w < wcnt) {
      const int s = w;
      const float m2 = mL[s][l31];
      const float l2 = lL[s][l31];
      const float M  = fmaxf(m, m2);
      const float a  = (l  > 0.f) ? exp2f(m - M)  : 0.f;   // guard exp2(-inf-(-inf))
      const float a2 = (l2 > 0.f) ? exp2f(m2 - M) : 0.f;
      #pragma unroll
      for (int r = 0; r < 16; ++r) {
        const int dr = (r & 3) + 8 * (r >> 2) + 4 * hi;
        o0[r] = o0[r] * a + OLs[s][l31][dr]      * a2;
        o1[r] = o1[r] * a + OLs[s][l31][dr + 32] * a2;
      }
      l = l * a + l2 * a2;
      m = M;
    }
    __syncthreads();
  }

  // wave 0 holds final (m,l,O^T): normalize into FIN, coalesced store
  if (w == 0) {
    const float rl = (l > 0.f) ? 1.0f / l : 0.0f;
    #pragma unroll
    for (int r = 0; r < 16; ++r) {
      const int dr = (r & 3) + 8 * (r >> 2) + 4 * hi;
      FIN[l31][dr]      = o0[r] * rl;
      FIN[l31][dr + 32] = o1[r] * rl;
    }
  }
  __syncthreads();
  const size_t base = ((size_t)b * Lq + (size_t)qt * QB) * DHEAD;
  for (int e = tid; e < QB * DHEAD; e += NW * 64)
    Og[base + e] = FIN[e >> 6][e & 63];
}

// ---- fallback (round-2 kernel, on-the-fly conversion) ----
__global__ __launch_bounds__(NWF * 64)
void fa_fwd(const float* __restrict__ Qg, const float* __restrict__ Kg,
            const float* __restrict__ Vg, const int* __restrict__ VL,
            float* __restrict__ Og, int Lq, int Lk) {
  __shared__ float OLs[NWF][QB][DHEAD + 1];
  __shared__ float mLs[NWF][QB];
  __shared__ float lLs[NWF][QB];

  const int tid  = threadIdx.x;
  const int w    = tid >> 6;
  const int lane = tid & 63;
  const int l31  = lane & 31;
  const int hi   = lane >> 5;
  const int q0   = blockIdx.x * QB;
  const int b    = blockIdx.y;
  const int vl   = VL[b];

  const float* Qb = Qg + (size_t)b * Lq * DHEAD;
  const float* Kb = Kg + (size_t)b * Lk * DHEAD;
  const float* Vb = Vg + (size_t)b * Lk * DHEAD;

  const float cQ = 0.125f * 1.4426950408889634f;
  short8 qf[4];
  {
    const float* qrow = Qb + (size_t)(q0 + l31) * DHEAD + hi * 8;
    #pragma unroll
    for (int kk = 0; kk < 4; ++kk) {
      Frag fr;
      #pragma unroll
      for (int j = 0; j < 4; ++j)
        fr.u[j] = pack2_bf16(qrow[kk * 16 + 2 * j] * cQ,
                             qrow[kk * 16 + 2 * j + 1] * cQ);
      qf[kk] = fr.s;
    }
  }

  f32x16 o0 = {};
  f32x16 o1 = {};
  float m = -INFINITY;
  float l = 0.0f;

  int nkb = (vl == 0) ? (Lk / KVB) : ((vl + KVB - 1) / KVB);
  if (nkb > Lk / KVB) nkb = Lk / KVB;
  const int nt = (nkb > w) ? ((nkb - w + NWF - 1) / NWF) : 0;

  const float MASKV = -1442695.04f;

  float kraw[32], vraw[32];

  if (nt > 0) {
    const float* krow = Kb + (size_t)(w * KVB + l31) * DHEAD + hi * 8;
    #pragma unroll
    for (int kk = 0; kk < 4; ++kk)
      #pragma unroll
      for (int j = 0; j < 8; ++j) kraw[kk * 8 + j] = krow[kk * 16 + j];
  }

  for (int t = 0; t < nt; ++t) {
    const int key0 = (w + t * NWF) * KVB;

    short8 kf[4];
    #pragma unroll
    for (int kk = 0; kk < 4; ++kk) {
      Frag fr;
      #pragma unroll
      for (int j = 0; j < 4; ++j)
        fr.u[j] = pack2_bf16(kraw[kk * 8 + 2 * j], kraw[kk * 8 + 2 * j + 1]);
      kf[kk] = fr.s;
    }

    #pragma unroll
    for (int kk = 0; kk < 2; ++kk) {
      const float* vrow = Vb + (size_t)(key0 + kk * 16 + hi * 8) * DHEAD + l31;
      #pragma unroll
      for (int j = 0; j < 8; ++j) {
        vraw[kk * 16 + j]     = vrow[j * DHEAD];
        vraw[kk * 16 + 8 + j] = vrow[j * DHEAD + 32];
      }
    }

    f32x16 s = {};
    #pragma unroll
    for (int kk = 0; kk < 4; ++kk)
      s = __builtin_amdgcn_mfma_f32_32x32x16_bf16(kf[kk], qf[kk], s, 0, 0, 0);

    if (t + 1 < nt) {
      const float* krow = Kb + (size_t)(key0 + NWF * KVB + l31) * DHEAD + hi * 8;
      #pragma unroll
      for (int kk = 0; kk < 4; ++kk)
        #pragma unroll
        for (int j = 0; j < 8; ++j) kraw[kk * 8 + j] = krow[kk * 16 + j];
    }

    if (key0 + KVB > vl) {
      #pragma unroll
      for (int r = 0; r < 16; ++r) {
        const int key = key0 + (r & 3) + 8 * (r >> 2) + 4 * hi;
        if (key >= vl) s[r] = MASKV;
      }
    }

    float t0 = fmaxf(s[0], s[1]),  t1 = fmaxf(s[2], s[3]);
    float t2 = fmaxf(s[4], s[5]),  t3 = fmaxf(s[6], s[7]);
    float t4 = fmaxf(s[8], s[9]),  t5 = fmaxf(s[10], s[11]);
    float t6 = fmaxf(s[12], s[13]), t7 = fmaxf(s[14], s[15]);
    t0 = fmaxf(t0, t1); t2 = fmaxf(t2, t3); t4 = fmaxf(t4, t5); t6 = fmaxf(t6, t7);
    t0 = fmaxf(t0, t2); t4 = fmaxf(t4, t6);
    float tm = fmaxf(t0, t4);
    tm = fmaxf(tm, __shfl_xor(tm, 32));
    const float mnew  = fmaxf(m, tm);
    const float alpha = exp2f(m - mnew);
    #pragma unroll
    for (int r = 0; r < 16; ++r) s[r] = exp2f(s[r] - mnew);
    float u0 = s[0] + s[1],  u1 = s[2] + s[3];
    float u2 = s[4] + s[5],  u3 = s[6] + s[7];
    float u4 = s[8] + s[9],  u5 = s[10] + s[11];
    float u6 = s[12] + s[13], u7 = s[14] + s[15];
    u0 += u1; u2 += u3; u4 += u5; u6 += u7; u0 += u2; u4 += u6;
    float sum = u0 + u4;
    sum += __shfl_xor(sum, 32);
    l = l * alpha + sum;
    m = mnew;
    #pragma unroll
    for (int r = 0; r < 16; ++r) { o0[r] *= alpha; o1[r] *= alpha; }

    short8 pf[2];
    #pragma unroll
    for (int kk = 0; kk < 2; ++kk) {
      const unsigned A0 = pack2_bf16(s[8 * kk + 0], s[8 * kk + 1]);
      const unsigned B0 = pack2_bf16(s[8 * kk + 2], s[8 * kk + 3]);
      const unsigned C0 = pack2_bf16(s[8 * kk + 4], s[8 * kk + 5]);
      const unsigned D0 = pack2_bf16(s[8 * kk + 6], s[8 * kk + 7]);
      const unsigned sA = (unsigned)__shfl_xor((int)A0, 32);
      const unsigned sB = (unsigned)__shfl_xor((int)B0, 32);
      const unsigned sC = (unsigned)__shfl_xor((int)C0, 32);
      const unsigned sD = (unsigned)__shfl_xor((int)D0, 32);
      Frag fr;
      fr.u[0] = hi ? sC : A0;
      fr.u[1] = hi ? sD : B0;
      fr.u[2] = hi ? C0 : sA;
      fr.u[3] = hi ? D0 : sB;
      pf[kk] = fr.s;
    }

    #pragma unroll
    for (int kk = 0; kk < 2; ++kk) {
      Frag f0, f1;
      #pragma unroll
      for (int j = 0; j < 4; ++j) {
        f0.u[j] = pack2_bf16(vraw[kk * 16 + 2 * j],     vraw[kk * 16 + 2 * j + 1]);
        f1.u[j] = pack2_bf16(vraw[kk * 16 + 8 + 2 * j], vraw[kk * 16 + 8 + 2 * j + 1]);
      }
      o0 = __builtin_amdgcn_mfma_f32_32x32x16_bf16(f0.s, pf[kk], o0, 0, 0, 0);
      o1 = __builtin_amdgcn_mfma_f32_32x32x16_bf16(f1.s, pf[kk], o1, 0, 0, 0);
    }
  }

  if (hi == 0) { mLs[w][l31] = m; lLs[w][l31] = l; }
  #pragma unroll
  for (int r = 0; r < 16; ++r) {
    const int dr = (r & 3) + 8 * (r >> 2) + 4 * hi;
    OLs[w][l31][dr]      = o0[r];
    OLs[w][l31][dr + 32] = o1[r];
  }
  __syncthreads();

  for (int e = tid; e < QB * DHEAD; e += NWF * 64) {
    const int q = e >> 6;
    const int d = e & 63;
    float M = mLs[0][q];
    #pragma unroll
    for (int ww = 1; ww < NWF; ++ww) M = fmaxf(M, mLs[ww][q]);
    float L = 0.f, acc = 0.f;
    #pragma unroll
    for (int ww = 0; ww < NWF; ++ww) {
      const float wgt = exp2f(mLs[ww][q] - M);
      L   += lLs[ww][q] * wgt;
      acc += OLs[ww][q][d] * wgt;
    }
    Og[((size_t)b * Lq + q0 + q) * DHEAD + d] = acc / L;
  }
}

extern "C" void kernel_launch(void* const* d_in, const int* in_sizes, int n_in,
                              void* d_out, int out_size, void* d_ws, size_t ws_size,
                              hipStream_t stream) {
  const float* Q  = (const float*)d_in[0];
  const float* K  = (const float*)d_in[1];
  const float* V  = (const float*)d_in[2];
  const int*   VL = (const int*)d_in[3];
  float* O = (float*)d_out;

  const int B  = in_sizes[3];                  // 8
  const int Lq = in_sizes[0] / (B * DHEAD);    // 2048
  const int Lk = in_sizes[1] / (B * DHEAD);    // 2048
  const int nqt = Lq / QB;                     // 64

  const size_t qfE = (size_t)B * Lq * DHEAD;   // elements
  const size_t kfE = (size_t)B * Lk * DHEAD;
  const size_t need = (qfE + kfE * 2) * 2;     // Qf + Kf + Vf (bf16)

  if (ws_size >= need) {
    unsigned short* Qf = (unsigned short*)d_ws;
    unsigned short* Kf = Qf + qfE;
    unsigned short* Vf = Kf + kfE;

    const int maxT = (Lq > Lk ? Lq : Lk) / 32;
    dim3 pgrid(maxT, B);
    prep_f<<<pgrid, 256, 0, stream>>>(Q, K, V, Qf, Kf, Vf, VL, Lq, Lk);
    fa8<<<dim3(nqt * B), NW * 64, 0, stream>>>(Qf, Kf, Vf, VL, O, Lq, Lk, nqt, B);
  } else {
    dim3 grid(Lq / QB, B);
    fa_fwd<<<grid, NWF * 64, 0, stream>>>(Q, K, V, VL, O, Lq, Lk);
  }
}

// Round 19
// 32.320 us; speedup vs baseline: 2.7897x; 1.2185x over previous
//
#include <hip/hip_runtime.h>
#include <hip/hip_bf16.h>
#include <math.h>

typedef __attribute__((ext_vector_type(8))) short short8;
typedef __attribute__((ext_vector_type(16))) float f32x16;

#define DHEAD 64
#define KVB 32
#define QB 32
#define NW 8     // waves per block (KV-split factor)
#define NWF 4    // fallback waves/block

// RNE fp32->bf16 pair pack (same rounding as v_cvt_pk_bf16_f32)
__device__ __forceinline__ unsigned pack2_bf16(float a, float b) {
  unsigned ua = __builtin_bit_cast(unsigned, a);
  unsigned ub = __builtin_bit_cast(unsigned, b);
  ua = (ua + 0x7fffu + ((ua >> 16) & 1u)) >> 16;
  ub = (ub + 0x7fffu + ((ub >> 16) & 1u)) >> 16;
  return (ua & 0xffffu) | (ub << 16);
}

union Frag { unsigned u[4]; short8 s; };

// ---- prep: Q,K,V -> bf16 PER-TILE FRAGMENT ORDER, NON-TEMPORAL stores (r15-proven) ----
__global__ __launch_bounds__(256)
void prep_f(const float* __restrict__ Q, const float* __restrict__ K,
            const float* __restrict__ V, unsigned short* __restrict__ Qf,
            unsigned short* __restrict__ Kf, unsigned short* __restrict__ Vf,
            const int* __restrict__ VL, int Lq, int Lk) {
  __shared__ float Vs[32][65];
  const int b = blockIdx.y, t = blockIdx.x, tid = threadIdx.x;
  const int LkT = Lk / 32, LqT = Lq / 32;
  const int kk = tid >> 6, lane = tid & 63;
  const int row = lane & 31, colb = kk * 16 + ((lane >> 5) & 1) * 8;
  const float cQ = 0.125f * 1.4426950408889634f;  // (1/sqrt(64))*log2(e)

  if (t < LqT) {
    const float* src = Q + (((size_t)b * Lq + t * 32 + row) * DHEAD + colb);
    Frag fr;
    #pragma unroll
    for (int j = 0; j < 4; ++j)
      fr.u[j] = pack2_bf16(src[2 * j] * cQ, src[2 * j + 1] * cQ);
    __builtin_nontemporal_store(fr.s, (short8*)(Qf + ((size_t)(b * LqT + t)) * 2048 + tid * 8));
  }

  const int vl = VL[b];
  int nkb = (vl == 0) ? LkT : ((vl + 31) / 32);
  if (nkb > LkT) nkb = LkT;

  if (t < nkb) {
    const size_t base = ((size_t)b * Lk + t * 32) * DHEAD;
    {  // K convert
      const float* src = K + base + (size_t)row * DHEAD + colb;
      Frag fr;
      #pragma unroll
      for (int j = 0; j < 4; ++j)
        fr.u[j] = pack2_bf16(src[2 * j], src[2 * j + 1]);
      __builtin_nontemporal_store(fr.s, (short8*)(Kf + ((size_t)(b * LkT + t)) * 2048 + tid * 8));
    }
    for (int e = tid; e < 32 * DHEAD; e += 256) Vs[e >> 6][e & 63] = V[base + e];
    __syncthreads();
    const int region = tid >> 6;              // 0..3 = half*2 + vkk
    const int vkk = region & 1, half = region >> 1;
    const int krow = vkk * 16 + ((lane >> 5) & 1) * 8;
    const int d = half * 32 + (lane & 31);
    Frag fv;
    #pragma unroll
    for (int j = 0; j < 4; ++j)
      fv.u[j] = pack2_bf16(Vs[krow + 2 * j][d], Vs[krow + 2 * j + 1][d]);
    __builtin_nontemporal_store(fv.s, (short8*)(Vf + ((size_t)(b * LkT + t)) * 2048 + tid * 8));
  }
}

// ---- one KV-tile step (r15-proven): V loads -> S MFMA -> K prefetch -> softmax -> PV ----
__device__ __forceinline__ void tile_body(
    int t, int nkb, int vl, int lane, int hi,
    const unsigned short* __restrict__ kb, const unsigned short* __restrict__ vb,
    const short8 (&qf)[4], short8 (&kc)[4], short8 (&kn)[4],
    f32x16& o0, f32x16& o1, float& m, float& l) {
  const float MASKV = -1442695.04f;  // -1e6 * log2(e)

  const unsigned short* vt = vb + (size_t)t * 2048;
  short8 vf0[2], vf1[2];
  #pragma unroll
  for (int kk = 0; kk < 2; ++kk) {
    vf0[kk] = *(const short8*)(vt + kk * 512 + lane * 8);
    vf1[kk] = *(const short8*)(vt + (2 + kk) * 512 + lane * 8);
  }

  f32x16 s = {};
  #pragma unroll
  for (int kk = 0; kk < 4; ++kk)
    s = __builtin_amdgcn_mfma_f32_32x32x16_bf16(kc[kk], qf[kk], s, 0, 0, 0);

  const int tn = t + NW;
  if (tn < nkb) {
    const unsigned short* ktn = kb + (size_t)tn * 2048;
    #pragma unroll
    for (int kk = 0; kk < 4; ++kk)
      kn[kk] = *(const short8*)(ktn + kk * 512 + lane * 8);
  }

  const int key0 = t * KVB;
  if (key0 + KVB > vl) {
    #pragma unroll
    for (int r = 0; r < 16; ++r) {
      const int key = key0 + (r & 3) + 8 * (r >> 2) + 4 * hi;
      if (key >= vl) s[r] = MASKV;
    }
  }

  float t0 = fmaxf(s[0], s[1]),  t1 = fmaxf(s[2], s[3]);
  float t2 = fmaxf(s[4], s[5]),  t3 = fmaxf(s[6], s[7]);
  float t4 = fmaxf(s[8], s[9]),  t5 = fmaxf(s[10], s[11]);
  float t6 = fmaxf(s[12], s[13]), t7 = fmaxf(s[14], s[15]);
  t0 = fmaxf(t0, t1); t2 = fmaxf(t2, t3); t4 = fmaxf(t4, t5); t6 = fmaxf(t6, t7);
  t0 = fmaxf(t0, t2); t4 = fmaxf(t4, t6);
  float tm = fmaxf(t0, t4);
  tm = fmaxf(tm, __shfl_xor(tm, 32));

  if (__any(tm > m)) {          // exact defer-max
    const float mnew  = fmaxf(m, tm);
    const float alpha = exp2f(m - mnew);  // first iter: exp2(-inf) = 0
    #pragma unroll
    for (int r = 0; r < 16; ++r) { o0[r] *= alpha; o1[r] *= alpha; }
    l *= alpha;
    m = mnew;
  }
  #pragma unroll
  for (int r = 0; r < 16; ++r) s[r] = exp2f(s[r] - m);
  float u0 = s[0] + s[1],  u1 = s[2] + s[3];
  float u2 = s[4] + s[5],  u3 = s[6] + s[7];
  float u4 = s[8] + s[9],  u5 = s[10] + s[11];
  float u6 = s[12] + s[13], u7 = s[14] + s[15];
  u0 += u1; u2 += u3; u4 += u5; u6 += u7; u0 += u2; u4 += u6;
  l += u0 + u4 + __shfl_xor(u0 + u4, 32);

  short8 pf[2];
  #pragma unroll
  for (int kk = 0; kk < 2; ++kk) {
    const unsigned A0 = pack2_bf16(s[8 * kk + 0], s[8 * kk + 1]);
    const unsigned B0 = pack2_bf16(s[8 * kk + 2], s[8 * kk + 3]);
    const unsigned C0 = pack2_bf16(s[8 * kk + 4], s[8 * kk + 5]);
    const unsigned D0 = pack2_bf16(s[8 * kk + 6], s[8 * kk + 7]);
    const unsigned sA = (unsigned)__shfl_xor((int)A0, 32);
    const unsigned sB = (unsigned)__shfl_xor((int)B0, 32);
    const unsigned sC = (unsigned)__shfl_xor((int)C0, 32);
    const unsigned sD = (unsigned)__shfl_xor((int)D0, 32);
    Frag fr;
    fr.u[0] = hi ? sC : A0;
    fr.u[1] = hi ? sD : B0;
    fr.u[2] = hi ? C0 : sA;
    fr.u[3] = hi ? D0 : sB;
    pf[kk] = fr.s;
  }

  #pragma unroll
  for (int kk = 0; kk < 2; ++kk) {
    o0 = __builtin_amdgcn_mfma_f32_32x32x16_bf16(vf0[kk], pf[kk], o0, 0, 0, 0);
    o1 = __builtin_amdgcn_mfma_f32_32x32x16_bf16(vf1[kk], pf[kk], o1, 0, 0, 0);
  }
}

// ---- fused pass (r15-proven): 2-D grid (qt, b); 8 waves split KV; no spill ----
__global__ __launch_bounds__(NW * 64, 2)
void fa8(const unsigned short* __restrict__ Qf, const unsigned short* __restrict__ Kf,
         const unsigned short* __restrict__ Vf, const int* __restrict__ VL,
         float* __restrict__ Og, int Lq, int Lk, int nqt) {
  __shared__ float OLs[4][QB][DHEAD + 1];   // staged tree-merge slots
  __shared__ float mL[4][QB];
  __shared__ float lL[4][QB];
  __shared__ float FIN[QB][DHEAD + 2];      // output coalescing buffer

  const int tid  = threadIdx.x;
  const int w    = tid >> 6;
  const int lane = tid & 63;
  const int l31  = lane & 31;
  const int hi   = lane >> 5;
  const int qt   = blockIdx.x;
  const int b    = blockIdx.y;
  const int vl   = VL[b];

  const int LkT = Lk / KVB;
  int nkb = (vl == 0) ? LkT : ((vl + KVB - 1) / KVB);
  if (nkb > LkT) nkb = LkT;

  const unsigned short* qtile = Qf + ((size_t)(b * nqt + qt)) * 2048;
  short8 qf[4];
  #pragma unroll
  for (int kk = 0; kk < 4; ++kk)
    qf[kk] = *(const short8*)(qtile + kk * 512 + lane * 8);

  const unsigned short* kb = Kf + (size_t)b * LkT * 2048;
  const unsigned short* vb = Vf + (size_t)b * LkT * 2048;

  f32x16 o0 = {};  // O^T rows d=0..31  (col = query = lane&31)
  f32x16 o1 = {};  // O^T rows d=32..63
  float m = -INFINITY;
  float l = 0.0f;

  // K double-buffer software pipeline (static indexing)
  int t = w;
  if (t < nkb) {
    short8 kA[4], kB[4];
    const unsigned short* kt = kb + (size_t)t * 2048;
    #pragma unroll
    for (int kk = 0; kk < 4; ++kk)
      kA[kk] = *(const short8*)(kt + kk * 512 + lane * 8);
    while (true) {
      tile_body(t, nkb, vl, lane, hi, kb, vb, qf, kA, kB, o0, o1, m, l);
      t += NW; if (t >= nkb) break;
      tile_body(t, nkb, vl, lane, hi, kb, vb, qf, kB, kA, o0, o1, m, l);
      t += NW; if (t >= nkb) break;
    }
  }

  // ---- staged pairwise tree merge, 4 slots, NaN-safe (l>0 guards) ----
  #pragma unroll
  for (int ph = 0; ph < 3; ++ph) {
    const int wlo  = (ph == 0) ? 4 : (ph == 1) ? 2 : 1;
    const int wcnt = wlo == 1 ? 1 : wlo;

    if (w >= wlo && w < wlo + wcnt) {
      const int s = w - wlo;
      if (hi == 0) { mL[s][l31] = m; lL[s][l31] = l; }
      #pragma unroll
      for (int r = 0; r < 16; ++r) {
        const int dr = (r & 3) + 8 * (r >> 2) + 4 * hi;
        OLs[s][l31][dr]      = o0[r];
        OLs[s][l31][dr + 32] = o1[r];
      }
    }
    __syncthreads();
    if (w < wcnt) {
      const int s = w;
      const float m2 = mL[s][l31];
      const float l2 = lL[s][l31];
      const float M  = fmaxf(m, m2);
      const float a  = (l  > 0.f) ? exp2f(m - M)  : 0.f;   // guard exp2(-inf-(-inf))
      const float a2 = (l2 > 0.f) ? exp2f(m2 - M) : 0.f;
      #pragma unroll
      for (int r = 0; r < 16; ++r) {
        const int dr = (r & 3) + 8 * (r >> 2) + 4 * hi;
        o0[r] = o0[r] * a + OLs[s][l31][dr]      * a2;
        o1[r] = o1[r] * a + OLs[s][l31][dr + 32] * a2;
      }
      l = l * a + l2 * a2;
      m = M;
    }
    __syncthreads();
  }

  // wave 0 holds final (m,l,O^T): normalize into FIN, coalesced store
  if (w == 0) {
    const float rl = (l > 0.f) ? 1.0f / l : 0.0f;
    #pragma unroll
    for (int r = 0; r < 16; ++r) {
      const int dr = (r & 3) + 8 * (r >> 2) + 4 * hi;
      FIN[l31][dr]      = o0[r] * rl;
      FIN[l31][dr + 32] = o1[r] * rl;
    }
  }
  __syncthreads();
  const size_t base = ((size_t)b * Lq + (size_t)qt * QB) * DHEAD;
  for (int e = tid; e < QB * DHEAD; e += NW * 64)
    Og[base + e] = FIN[e >> 6][e & 63];
}

// ---- fallback (round-2 kernel, on-the-fly conversion) ----
__global__ __launch_bounds__(NWF * 64)
void fa_fwd(const float* __restrict__ Qg, const float* __restrict__ Kg,
            const float* __restrict__ Vg, const int* __restrict__ VL,
            float* __restrict__ Og, int Lq, int Lk) {
  __shared__ float OLs[NWF][QB][DHEAD + 1];
  __shared__ float mLs[NWF][QB];
  __shared__ float lLs[NWF][QB];

  const int tid  = threadIdx.x;
  const int w    = tid >> 6;
  const int lane = tid & 63;
  const int l31  = lane & 31;
  const int hi   = lane >> 5;
  const int q0   = blockIdx.x * QB;
  const int b    = blockIdx.y;
  const int vl   = VL[b];

  const float* Qb = Qg + (size_t)b * Lq * DHEAD;
  const float* Kb = Kg + (size_t)b * Lk * DHEAD;
  const float* Vb = Vg + (size_t)b * Lk * DHEAD;

  const float cQ = 0.125f * 1.4426950408889634f;
  short8 qf[4];
  {
    const float* qrow = Qb + (size_t)(q0 + l31) * DHEAD + hi * 8;
    #pragma unroll
    for (int kk = 0; kk < 4; ++kk) {
      Frag fr;
      #pragma unroll
      for (int j = 0; j < 4; ++j)
        fr.u[j] = pack2_bf16(qrow[kk * 16 + 2 * j] * cQ,
                             qrow[kk * 16 + 2 * j + 1] * cQ);
      qf[kk] = fr.s;
    }
  }

  f32x16 o0 = {};
  f32x16 o1 = {};
  float m = -INFINITY;
  float l = 0.0f;

  int nkb = (vl == 0) ? (Lk / KVB) : ((vl + KVB - 1) / KVB);
  if (nkb > Lk / KVB) nkb = Lk / KVB;
  const int nt = (nkb > w) ? ((nkb - w + NWF - 1) / NWF) : 0;

  const float MASKV = -1442695.04f;

  float kraw[32], vraw[32];

  if (nt > 0) {
    const float* krow = Kb + (size_t)(w * KVB + l31) * DHEAD + hi * 8;
    #pragma unroll
    for (int kk = 0; kk < 4; ++kk)
      #pragma unroll
      for (int j = 0; j < 8; ++j) kraw[kk * 8 + j] = krow[kk * 16 + j];
  }

  for (int t = 0; t < nt; ++t) {
    const int key0 = (w + t * NWF) * KVB;

    short8 kf[4];
    #pragma unroll
    for (int kk = 0; kk < 4; ++kk) {
      Frag fr;
      #pragma unroll
      for (int j = 0; j < 4; ++j)
        fr.u[j] = pack2_bf16(kraw[kk * 8 + 2 * j], kraw[kk * 8 + 2 * j + 1]);
      kf[kk] = fr.s;
    }

    #pragma unroll
    for (int kk = 0; kk < 2; ++kk) {
      const float* vrow = Vb + (size_t)(key0 + kk * 16 + hi * 8) * DHEAD + l31;
      #pragma unroll
      for (int j = 0; j < 8; ++j) {
        vraw[kk * 16 + j]     = vrow[j * DHEAD];
        vraw[kk * 16 + 8 + j] = vrow[j * DHEAD + 32];
      }
    }

    f32x16 s = {};
    #pragma unroll
    for (int kk = 0; kk < 4; ++kk)
      s = __builtin_amdgcn_mfma_f32_32x32x16_bf16(kf[kk], qf[kk], s, 0, 0, 0);

    if (t + 1 < nt) {
      const float* krow = Kb + (size_t)(key0 + NWF * KVB + l31) * DHEAD + hi * 8;
      #pragma unroll
      for (int kk = 0; kk < 4; ++kk)
        #pragma unroll
        for (int j = 0; j < 8; ++j) kraw[kk * 8 + j] = krow[kk * 16 + j];
    }

    if (key0 + KVB > vl) {
      #pragma unroll
      for (int r = 0; r < 16; ++r) {
        const int key = key0 + (r & 3) + 8 * (r >> 2) + 4 * hi;
        if (key >= vl) s[r] = MASKV;
      }
    }

    float t0 = fmaxf(s[0], s[1]),  t1 = fmaxf(s[2], s[3]);
    float t2 = fmaxf(s[4], s[5]),  t3 = fmaxf(s[6], s[7]);
    float t4 = fmaxf(s[8], s[9]),  t5 = fmaxf(s[10], s[11]);
    float t6 = fmaxf(s[12], s[13]), t7 = fmaxf(s[14], s[15]);
    t0 = fmaxf(t0, t1); t2 = fmaxf(t2, t3); t4 = fmaxf(t4, t5); t6 = fmaxf(t6, t7);
    t0 = fmaxf(t0, t2); t4 = fmaxf(t4, t6);
    float tm = fmaxf(t0, t4);
    tm = fmaxf(tm, __shfl_xor(tm, 32));
    const float mnew  = fmaxf(m, tm);
    const float alpha = exp2f(m - mnew);
    #pragma unroll
    for (int r = 0; r < 16; ++r) s[r] = exp2f(s[r] - mnew);
    float u0 = s[0] + s[1],  u1 = s[2] + s[3];
    float u2 = s[4] + s[5],  u3 = s[6] + s[7];
    float u4 = s[8] + s[9],  u5 = s[10] + s[11];
    float u6 = s[12] + s[13], u7 = s[14] + s[15];
    u0 += u1; u2 += u3; u4 += u5; u6 += u7; u0 += u2; u4 += u6;
    float sum = u0 + u4;
    sum += __shfl_xor(sum, 32);
    l = l * alpha + sum;
    m = mnew;
    #pragma unroll
    for (int r = 0; r < 16; ++r) { o0[r] *= alpha; o1[r] *= alpha; }

    short8 pf[2];
    #pragma unroll
    for (int kk = 0; kk < 2; ++kk) {
      const unsigned A0 = pack2_bf16(s[8 * kk + 0], s[8 * kk + 1]);
      const unsigned B0 = pack2_bf16(s[8 * kk + 2], s[8 * kk + 3]);
      const unsigned C0 = pack2_bf16(s[8 * kk + 4], s[8 * kk + 5]);
      const unsigned D0 = pack2_bf16(s[8 * kk + 6], s[8 * kk + 7]);
      const unsigned sA = (unsigned)__shfl_xor((int)A0, 32);
      const unsigned sB = (unsigned)__shfl_xor((int)B0, 32);
      const unsigned sC = (unsigned)__shfl_xor((int)C0, 32);
      const unsigned sD = (unsigned)__shfl_xor((int)D0, 32);
      Frag fr;
      fr.u[0] = hi ? sC : A0;
      fr.u[1] = hi ? sD : B0;
      fr.u[2] = hi ? C0 : sA;
      fr.u[3] = hi ? D0 : sB;
      pf[kk] = fr.s;
    }

    #pragma unroll
    for (int kk = 0; kk < 2; ++kk) {
      Frag f0, f1;
      #pragma unroll
      for (int j = 0; j < 4; ++j) {
        f0.u[j] = pack2_bf16(vraw[kk * 16 + 2 * j],     vraw[kk * 16 + 2 * j + 1]);
        f1.u[j] = pack2_bf16(vraw[kk * 16 + 8 + 2 * j], vraw[kk * 16 + 8 + 2 * j + 1]);
      }
      o0 = __builtin_amdgcn_mfma_f32_32x32x16_bf16(f0.s, pf[kk], o0, 0, 0, 0);
      o1 = __builtin_amdgcn_mfma_f32_32x32x16_bf16(f1.s, pf[kk], o1, 0, 0, 0);
    }
  }

  if (hi == 0) { mLs[w][l31] = m; lLs[w][l31] = l; }
  #pragma unroll
  for (int r = 0; r < 16; ++r) {
    const int dr = (r & 3) + 8 * (r >> 2) + 4 * hi;
    OLs[w][l31][dr]      = o0[r];
    OLs[w][l31][dr + 32] = o1[r];
  }
  __syncthreads();

  for (int e = tid; e < QB * DHEAD; e += NWF * 64) {
    const int q = e >> 6;
    const int d = e & 63;
    float M = mLs[0][q];
    #pragma unroll
    for (int ww = 1; ww < NWF; ++ww) M = fmaxf(M, mLs[ww][q]);
    float L = 0.f, acc = 0.f;
    #pragma unroll
    for (int ww = 0; ww < NWF; ++ww) {
      const float wgt = exp2f(mLs[ww][q] - M);
      L   += lLs[ww][q] * wgt;
      acc += OLs[ww][q][d] * wgt;
    }
    Og[((size_t)b * Lq + q0 + q) * DHEAD + d] = acc / L;
  }
}

extern "C" void kernel_launch(void* const* d_in, const int* in_sizes, int n_in,
                              void* d_out, int out_size, void* d_ws, size_t ws_size,
                              hipStream_t stream) {
  const float* Q  = (const float*)d_in[0];
  const float* K  = (const float*)d_in[1];
  const float* V  = (const float*)d_in[2];
  const int*   VL = (const int*)d_in[3];
  float* O = (float*)d_out;

  const int B  = in_sizes[3];                  // 8
  const int Lq = in_sizes[0] / (B * DHEAD);    // 2048
  const int Lk = in_sizes[1] / (B * DHEAD);    // 2048
  const int nqt = Lq / QB;                     // 64

  const size_t qfE = (size_t)B * Lq * DHEAD;   // elements
  const size_t kfE = (size_t)B * Lk * DHEAD;
  const size_t need = (qfE + kfE * 2) * 2;     // Qf + Kf + Vf (bf16)

  if (ws_size >= need) {
    unsigned short* Qf = (unsigned short*)d_ws;
    unsigned short* Kf = Qf + qfE;
    unsigned short* Vf = Kf + kfE;

    const int maxT = (Lq > Lk ? Lq : Lk) / 32;
    dim3 pgrid(maxT, B);
    prep_f<<<pgrid, 256, 0, stream>>>(Q, K, V, Qf, Kf, Vf, VL, Lq, Lk);
    dim3 g1(nqt, B);
    fa8<<<g1, NW * 64, 0, stream>>>(Qf, Kf, Vf, VL, O, Lq, Lk, nqt);
  } else {
    dim3 grid(Lq / QB, B);
    fa_fwd<<<grid, NWF * 64, 0, stream>>>(Q, K, V, VL, O, Lq, Lk);
  }
}